// Round 17
// baseline (87.935 us; speedup 1.0000x reference)
//
#include <hip/hip_runtime.h>

#define NB 16384
#define TT 10
#define DIN 256
#define HH 16
#define NG 64      // 4*H
#define NF 160     // T*H

typedef __attribute__((ext_vector_type(8))) _Float16 half8;
typedef __attribute__((ext_vector_type(4))) _Float16 half4;
typedef __attribute__((ext_vector_type(4))) float f32x4;
typedef unsigned int u32;

__device__ __forceinline__ void gld16(const float* g, float* l) {
    __builtin_amdgcn_global_load_lds(
        (const __attribute__((address_space(1))) u32*)g,
        (__attribute__((address_space(3))) u32*)l, 16, 0, 0);
}
__device__ __forceinline__ float sigf(float x) { return 1.0f / (1.0f + __expf(-x)); }
__device__ __forceinline__ float tanhf_(float x) {
    float e = __expf(2.0f * x);
    return 1.0f - 2.0f / (e + 1.0f);
}

// K0: prep (validated R14). Wih0 fragments fp16 lane order:
// Bf[(c*8+s)*64+l] = W[gate=c*16+(l&15)][k=s*32+(l>>4)*8+j]; recurrence
// A-fragments recw[m][c*64+l] = M[c*16+(l&15)][(l>>4)*4+j]; fused biases.
__global__ __launch_bounds__(256) void k_prep(
        const float* __restrict__ w, const float* __restrict__ bi,
        const float* __restrict__ bh, const float* __restrict__ whh0,
        const float* __restrict__ wih1, const float* __restrict__ whh1,
        const float* __restrict__ bi1, const float* __restrict__ bh1,
        half8* __restrict__ Bf, float* __restrict__ bsum,
        half4* __restrict__ recw, float* __restrict__ b1s) {
    const int fi = blockIdx.x * 256 + threadIdx.x;   // 0..2047
    {
        const int c = fi >> 9;
        const int s = (fi >> 6) & 7;
        const int ll = fi & 63;
        const int row = c * 16 + (ll & 15);
        const int k0 = s * 32 + ((ll >> 4) << 3);
        const float* wp = w + (size_t)row * DIN + k0;
        float4 a = *(const float4*)wp;
        float4 b = *(const float4*)(wp + 4);
        half8 h;
        h[0] = (_Float16)a.x; h[1] = (_Float16)a.y;
        h[2] = (_Float16)a.z; h[3] = (_Float16)a.w;
        h[4] = (_Float16)b.x; h[5] = (_Float16)b.y;
        h[6] = (_Float16)b.z; h[7] = (_Float16)b.w;
        Bf[fi] = h;
    }
    if (blockIdx.x < 3) {
        const float* M = blockIdx.x == 0 ? whh0 : (blockIdx.x == 1 ? wih1 : whh1);
        const int c = threadIdx.x >> 6;
        const int ll = threadIdx.x & 63;
        float4 v = *(const float4*)(M + (size_t)(c * 16 + (ll & 15)) * HH + ((ll >> 4) << 2));
        half4 h4;
        h4[0] = (_Float16)v.x; h4[1] = (_Float16)v.y;
        h4[2] = (_Float16)v.z; h4[3] = (_Float16)v.w;
        recw[blockIdx.x * 256 + c * 64 + ll] = h4;
    }
    if (blockIdx.x == 3 && threadIdx.x < NG) {
        bsum[threadIdx.x] = bi[threadIdx.x] + bh[threadIdx.x];
        b1s[threadIdx.x] = bi1[threadIdx.x] + bh1[threadIdx.x];
    }
}

// K1: MEGAFUSED proj + 2-layer LSTM, T-SPLIT roles.
// Block = 256 thr = 4 waves = 2 sample-groups x 2 roles.
// Role A (wave even): R14-exact proj+recurrence for t=0..4, then finishes
// t=5..9 from LDS. Role B (wave odd): proj-only t=5..9 -> proj+bias acc
// (f32, bit-exact) to LDS. One mid syncthreads; no per-step barriers.
// 72KB LDS -> 2 blocks/CU -> 2 waves/SIMD (2x R14 in-flight).
__global__ __launch_bounds__(256, 2) void k_mega(
        const float* __restrict__ x, const half8* __restrict__ Bf,
        const float* __restrict__ bsum, const half4* __restrict__ recw,
        const float* __restrict__ b1s, _Float16* __restrict__ flatT) {
    __shared__ half8 Bl[2048];        // 32 KB Wih0 fragments
    __shared__ float xgl[2][5120];    // 2 groups x 20 KB: [t-5][c][lane][r]
    const int tid = threadIdx.x;
    const int l = tid & 63;
    const int w = tid >> 6;
    const int g = w >> 1;
    const int role = w & 1;           // 0: t0-4 + recurrence; 1: t5-9 proj

    #pragma unroll
    for (int q = 0; q < 8; ++q)
        gld16((const float*)(Bf + (w * 8 + q) * 64 + l),
              (float*)(Bl + (w * 8 + q) * 64));

    half4 w0f[4], w1f[4], w2f[4];
    f32x4 b0[4], b1[4];
    #pragma unroll
    for (int c = 0; c < 4; ++c) {
        w0f[c] = recw[0 * 256 + c * 64 + l];
        w1f[c] = recw[1 * 256 + c * 64 + l];
        w2f[c] = recw[2 * 256 + c * 64 + l];
        b0[c] = *(const f32x4*)(bsum + c * 16 + ((l >> 4) << 2));
        b1[c] = *(const f32x4*)(b1s + c * 16 + ((l >> 4) << 2));
    }
    __syncthreads();   // Bl staged

    const int sb = blockIdx.x * 2 + g;    // sample-group 0..1023
    const int tbase = role ? 5 : 0;
    const float* xp = x + (size_t)(sb * 16 + (l & 15)) * TT * DIN
                        + (size_t)tbase * DIN + ((l >> 4) << 3);
    float* xgq = &xgl[g][0];

    f32x4 A0[8], B0[8], A1[8], B1[8];
    #pragma unroll
    for (int s = 0; s < 8; ++s) {
        A0[s] = *(const f32x4*)(xp + s * 32);
        B0[s] = *(const f32x4*)(xp + s * 32 + 4);
    }

    half4 h0f, h1f;
    #pragma unroll
    for (int j = 0; j < 4; ++j) { h0f[j] = (_Float16)0.0f; h1f[j] = (_Float16)0.0f; }
    f32x4 cs0 = (f32x4)0.0f, cs1 = (f32x4)0.0f;

// shared proj core: compute ac0 = b0 + Wih0.x(t) from CA/CB, prefetch i+1
#define PROJ(i, CA, CB, NA, NB2, ac0)                                          \
        if ((i) < 4) {                                                         \
            _Pragma("unroll")                                                  \
            for (int s = 0; s < 8; ++s) {                                      \
                NA[s] = *(const f32x4*)(xp + ((i) + 1) * DIN + s * 32);        \
                NB2[s] = *(const f32x4*)(xp + ((i) + 1) * DIN + s * 32 + 4);   \
            }                                                                  \
        }                                                                      \
        _Pragma("unroll")                                                      \
        for (int s = 0; s < 8; ++s) {                                          \
            float fv[8] = {CA[s].x, CA[s].y, CA[s].z, CA[s].w,                 \
                           CB[s].x, CB[s].y, CB[s].z, CB[s].w};                \
            half8 xh, xl;                                                      \
            _Pragma("unroll")                                                  \
            for (int j = 0; j < 8; ++j) {                                      \
                _Float16 hi = (_Float16)fv[j];                                 \
                xh[j] = hi;                                                    \
                xl[j] = (_Float16)(fv[j] - (float)hi);                         \
            }                                                                  \
            _Pragma("unroll")                                                  \
            for (int c = 0; c < 4; ++c) {                                      \
                half8 wf = Bl[(c * 8 + s) * 64 + l];                           \
                ac0[c] = __builtin_amdgcn_mfma_f32_16x16x32_f16(wf, xh, ac0[c], 0, 0, 0); \
                ac0[c] = __builtin_amdgcn_mfma_f32_16x16x32_f16(wf, xl, ac0[c], 0, 0, 0); \
            }                                                                  \
        }

// recurrence core on ac0 (adds h-feedback, both layers, stores flatT at gt)
#define REC(gt, ac0)                                                           \
        _Pragma("unroll")                                                      \
        for (int c = 0; c < 4; ++c)                                            \
            ac0[c] = __builtin_amdgcn_mfma_f32_16x16x16f16(w0f[c], h0f, ac0[c], 0, 0, 0); \
        f32x4 h0v;                                                             \
        _Pragma("unroll")                                                      \
        for (int r = 0; r < 4; ++r) {                                          \
            float iv = sigf(ac0[0][r]), fg = sigf(ac0[1][r]);                  \
            float gv = tanhf_(ac0[2][r]), ov = sigf(ac0[3][r]);                \
            cs0[r] = fg * cs0[r] + iv * gv;                                    \
            h0v[r] = ov * tanhf_(cs0[r]);                                      \
        }                                                                      \
        h0f[0] = (_Float16)h0v[0]; h0f[1] = (_Float16)h0v[1];                  \
        h0f[2] = (_Float16)h0v[2]; h0f[3] = (_Float16)h0v[3];                  \
        f32x4 ac1[4] = {b1[0], b1[1], b1[2], b1[3]};                           \
        _Pragma("unroll")                                                      \
        for (int c = 0; c < 4; ++c) {                                          \
            ac1[c] = __builtin_amdgcn_mfma_f32_16x16x16f16(w1f[c], h0f, ac1[c], 0, 0, 0); \
            ac1[c] = __builtin_amdgcn_mfma_f32_16x16x16f16(w2f[c], h1f, ac1[c], 0, 0, 0); \
        }                                                                      \
        f32x4 h1v;                                                             \
        _Pragma("unroll")                                                      \
        for (int r = 0; r < 4; ++r) {                                          \
            float iv = sigf(ac1[0][r]), fg = sigf(ac1[1][r]);                  \
            float gv = tanhf_(ac1[2][r]), ov = sigf(ac1[3][r]);                \
            cs1[r] = fg * cs1[r] + iv * gv;                                    \
            h1v[r] = ov * tanhf_(cs1[r]);                                      \
        }                                                                      \
        h1f[0] = (_Float16)h1v[0]; h1f[1] = (_Float16)h1v[1];                  \
        h1f[2] = (_Float16)h1v[2]; h1f[3] = (_Float16)h1v[3];                  \
        _Pragma("unroll")                                                      \
        for (int r = 0; r < 4; ++r)                                            \
            flatT[(size_t)((gt) * 16 + ((l >> 4) << 2) + r) * NB + sb * 16 + (l & 15)] = (_Float16)h1v[r];

    if (role == 0) {
        // t = 0..4: R14-exact proj + recurrence
#define ASTEP(i, CA, CB, NA, NB2)                                              \
        {                                                                      \
            f32x4 ac0[4] = {b0[0], b0[1], b0[2], b0[3]};                       \
            PROJ(i, CA, CB, NA, NB2, ac0)                                      \
            REC(i, ac0)                                                        \
        }
        ASTEP(0, A0, B0, A1, B1)
        ASTEP(1, A1, B1, A0, B0)
        ASTEP(2, A0, B0, A1, B1)
        ASTEP(3, A1, B1, A0, B0)
        ASTEP(4, A0, B0, A1, B1)
#undef ASTEP
    } else {
        // t = 5..9: proj only, deposit proj+bias acc (f32) to LDS
#define BSTEP(i, CA, CB, NA, NB2)                                              \
        {                                                                      \
            f32x4 ac0[4] = {b0[0], b0[1], b0[2], b0[3]};                       \
            PROJ(i, CA, CB, NA, NB2, ac0)                                      \
            _Pragma("unroll")                                                  \
            for (int c = 0; c < 4; ++c)                                        \
                *(f32x4*)(xgq + (i) * 1024 + c * 256 + l * 4) = ac0[c];        \
        }
        BSTEP(0, A0, B0, A1, B1)
        BSTEP(1, A1, B1, A0, B0)
        BSTEP(2, A0, B0, A1, B1)
        BSTEP(3, A1, B1, A0, B0)
        BSTEP(4, A0, B0, A1, B1)
#undef BSTEP
    }
    __syncthreads();   // role B's xg(t5-9) visible

    if (role == 0) {
        // t = 5..9: recurrence from LDS-held proj accs (identical math)
#define TSTEP(tt)                                                              \
        {                                                                      \
            f32x4 ac0[4];                                                      \
            _Pragma("unroll")                                                  \
            for (int c = 0; c < 4; ++c)                                        \
                ac0[c] = *(const f32x4*)(xgq + (tt) * 1024 + c * 256 + l * 4); \
            REC((tt) + 5, ac0)                                                 \
        }
        TSTEP(0)
        TSTEP(1)
        TSTEP(2)
        TSTEP(3)
        TSTEP(4)
#undef TSTEP
    }
#undef PROJ
#undef REC
}

// K2: BN stats directly from column-major flatT (coalesced).
__global__ __launch_bounds__(256) void k_bn(
        const _Float16* __restrict__ flatT, const float* __restrict__ gamma,
        const float* __restrict__ beta, float* __restrict__ scale,
        float* __restrict__ shift) {
    const int f = blockIdx.x;
    const int tid = threadIdx.x;
    const _Float16* col = flatT + (size_t)f * NB;
    float s = 0.0f, q = 0.0f;
    #pragma unroll 8
    for (int i = tid; i < NB; i += 256) {
        float v = (float)col[i];
        s += v; q += v * v;
    }
    #pragma unroll
    for (int o = 32; o > 0; o >>= 1) {
        s += __shfl_down(s, o, 64);
        q += __shfl_down(q, o, 64);
    }
    __shared__ float rs[4], rq[4];
    const int wv = tid >> 6;
    if ((tid & 63) == 0) { rs[wv] = s; rq[wv] = q; }
    __syncthreads();
    if (tid == 0) {
        float S = rs[0] + rs[1] + rs[2] + rs[3];
        float Q = rq[0] + rq[1] + rq[2] + rq[3];
        float mean = S * (1.0f / NB);
        float var = Q * (1.0f / NB) - mean * mean;
        float sc = gamma[f] * rsqrtf(var + 1e-5f);
        scale[f] = sc;
        shift[f] = beta[f] - mean * sc;
    }
}

// K3: BN-apply + LeakyReLU + concat + FC(162->2) + softmax.
// One thread per sample; flatT reads coalesced; scalar weights.
__global__ __launch_bounds__(256) void k_fc(
        const _Float16* __restrict__ flatT, const float* __restrict__ scale,
        const float* __restrict__ shift, const float* __restrict__ ag,
        const float* __restrict__ fcw, const float* __restrict__ fcb,
        float* __restrict__ out) {
    const int smp = blockIdx.x * 256 + threadIdx.x;
    float p0 = 0.0f, p1 = 0.0f;
    #pragma unroll 8
    for (int f = 0; f < NF; ++f) {
        float xn = (float)flatT[(size_t)f * NB + smp] * scale[f] + shift[f];
        float a = xn >= 0.0f ? xn : 0.01f * xn;
        p0 += a * fcw[f];
        p1 += a * fcw[162 + f];
    }
    float a0 = ag[(size_t)smp * 2 + 0], a1 = ag[(size_t)smp * 2 + 1];
    float l0 = p0 + a0 * fcw[160] + a1 * fcw[161] + fcb[0];
    float l1 = p1 + a0 * fcw[162 + 160] + a1 * fcw[162 + 161] + fcb[1];
    float m = fmaxf(l0, l1);
    float e0 = __expf(l0 - m), e1 = __expf(l1 - m);
    float inv = 1.0f / (e0 + e1);
    out[(size_t)smp * 2 + 0] = e0 * inv;
    out[(size_t)smp * 2 + 1] = e1 * inv;
}

extern "C" void kernel_launch(void* const* d_in, const int* in_sizes, int n_in,
                              void* d_out, int out_size, void* d_ws, size_t ws_size,
                              hipStream_t stream) {
    const float* x     = (const float*)d_in[0];
    const float* ag    = (const float*)d_in[1];
    const float* wih0  = (const float*)d_in[2];
    const float* whh0  = (const float*)d_in[3];
    const float* bih0  = (const float*)d_in[4];
    const float* bhh0  = (const float*)d_in[5];
    const float* wih1  = (const float*)d_in[6];
    const float* whh1  = (const float*)d_in[7];
    const float* bih1  = (const float*)d_in[8];
    const float* bhh1  = (const float*)d_in[9];
    const float* gamma = (const float*)d_in[10];
    const float* beta  = (const float*)d_in[11];
    const float* fcw   = (const float*)d_in[12];
    const float* fcb   = (const float*)d_in[13];
    float* out = (float*)d_out;

    float* ws = (float*)d_ws;
    _Float16* flatT = (_Float16*)ws;           // 160 x 16384 halfs = 1,310,720 slots
    half8* Bf    = (half8*)(ws + 1310720);     // 8,192 slots (32 KB)
    half4* recw  = (half4*)(ws + 1318912);     // 1,536 slots
    float* bsum  = ws + 1320448;               // 64
    float* b1s   = ws + 1320512;               // 64
    float* scale = ws + 1320576;               // 160
    float* shift = ws + 1320736;               // 160

    k_prep<<<dim3(8),   dim3(256), 0, stream>>>(wih0, bih0, bhh0, whh0, wih1, whh1,
                                                bih1, bhh1, Bf, bsum, recw, b1s);
    k_mega<<<dim3(512), dim3(256), 0, stream>>>(x, Bf, bsum, recw, b1s, flatT);
    k_bn<<<dim3(NF),    dim3(256), 0, stream>>>(flatT, gamma, beta, scale, shift);
    k_fc<<<dim3(64),    dim3(256), 0, stream>>>(flatT, scale, shift, ag, fcw, fcb, out);
}

// Round 19
// 54.695 us; speedup vs baseline: 1.6077x; 1.6077x over previous
//
#include <hip/hip_runtime.h>

#define NB 16384
#define TT 10
#define DIN 256
#define HH 16
#define NG 64      // 4*H
#define NF 160     // T*H

typedef __attribute__((ext_vector_type(8))) _Float16 half8;
typedef __attribute__((ext_vector_type(4))) _Float16 half4;
typedef __attribute__((ext_vector_type(4))) float f32x4;

__device__ __forceinline__ float sigf(float x) { return 1.0f / (1.0f + __expf(-x)); }
__device__ __forceinline__ float tanhf_(float x) {
    float e = __expf(2.0f * x);
    return 1.0f - 2.0f / (e + 1.0f);
}

// K1: MEGAFUSED proj + 2-layer LSTM (R14-exact K-loop) with SELF-PREP:
// each block converts Wih0 into LDS fragments and computes recurrence
// fragments/biases per-thread (bit-identical to the old k_prep math) —
// no prep kernel, no Bf/recw global round-trip, one fewer launch.
// One wave = 16 samples; C[gate][sample] orientation; identity h-feedback.
__global__ __launch_bounds__(256, 1) void k_mega(
        const float* __restrict__ x, const float* __restrict__ wih0,
        const float* __restrict__ bih0, const float* __restrict__ bhh0,
        const float* __restrict__ whh0, const float* __restrict__ wih1,
        const float* __restrict__ whh1, const float* __restrict__ bi1,
        const float* __restrict__ bh1, _Float16* __restrict__ flatT) {
    __shared__ half8 Bl[2048];   // 32 KB Wih0 fragments
    const int tid = threadIdx.x;
    const int l = tid & 63;
    const int wv = tid >> 6;

    // ---- self-prep: Wih0 fragments -> Bl (validated k_prep mapping) ----
    #pragma unroll
    for (int q = 0; q < 8; ++q) {
        const int fi = q * 256 + tid;          // 0..2047
        const int c = fi >> 9;
        const int s = (fi >> 6) & 7;
        const int ll = fi & 63;
        const int row = c * 16 + (ll & 15);
        const int k0 = s * 32 + ((ll >> 4) << 3);
        const float* wp = wih0 + (size_t)row * DIN + k0;
        float4 a = *(const float4*)wp;
        float4 b = *(const float4*)(wp + 4);
        half8 h;
        h[0] = (_Float16)a.x; h[1] = (_Float16)a.y;
        h[2] = (_Float16)a.z; h[3] = (_Float16)a.w;
        h[4] = (_Float16)b.x; h[5] = (_Float16)b.y;
        h[6] = (_Float16)b.z; h[7] = (_Float16)b.w;
        Bl[fi] = h;
    }

    // ---- recurrence fragments + fused biases, per-thread (k_prep math) ----
    half4 w0f[4], w1f[4], w2f[4];
    f32x4 b0[4], b1[4];
    #pragma unroll
    for (int c = 0; c < 4; ++c) {
        const int mrow = c * 16 + (l & 15);
        const int mk = (l >> 4) << 2;
        float4 v0 = *(const float4*)(whh0 + (size_t)mrow * HH + mk);
        w0f[c][0] = (_Float16)v0.x; w0f[c][1] = (_Float16)v0.y;
        w0f[c][2] = (_Float16)v0.z; w0f[c][3] = (_Float16)v0.w;
        float4 v1 = *(const float4*)(wih1 + (size_t)mrow * HH + mk);
        w1f[c][0] = (_Float16)v1.x; w1f[c][1] = (_Float16)v1.y;
        w1f[c][2] = (_Float16)v1.z; w1f[c][3] = (_Float16)v1.w;
        float4 v2 = *(const float4*)(whh1 + (size_t)mrow * HH + mk);
        w2f[c][0] = (_Float16)v2.x; w2f[c][1] = (_Float16)v2.y;
        w2f[c][2] = (_Float16)v2.z; w2f[c][3] = (_Float16)v2.w;
        const int bofs = c * 16 + mk;
        float4 vi0 = *(const float4*)(bih0 + bofs);
        float4 vh0 = *(const float4*)(bhh0 + bofs);
        b0[c][0] = vi0.x + vh0.x; b0[c][1] = vi0.y + vh0.y;
        b0[c][2] = vi0.z + vh0.z; b0[c][3] = vi0.w + vh0.w;
        float4 vi1 = *(const float4*)(bi1 + bofs);
        float4 vh1 = *(const float4*)(bh1 + bofs);
        b1[c][0] = vi1.x + vh1.x; b1[c][1] = vi1.y + vh1.y;
        b1[c][2] = vi1.z + vh1.z; b1[c][3] = vi1.w + vh1.w;
    }
    __syncthreads();   // Bl ready

    const int sb = blockIdx.x * 4 + wv;              // sample-group 0..1023
    const float* xp = x + (size_t)(sb * 16 + (l & 15)) * TT * DIN + ((l >> 4) << 3);

    f32x4 A0[8], B0[8], A1[8], B1[8];
    #pragma unroll
    for (int s = 0; s < 8; ++s) {
        A0[s] = *(const f32x4*)(xp + s * 32);
        B0[s] = *(const f32x4*)(xp + s * 32 + 4);
    }

    half4 h0f, h1f;
    #pragma unroll
    for (int j = 0; j < 4; ++j) { h0f[j] = (_Float16)0.0f; h1f[j] = (_Float16)0.0f; }
    f32x4 cs0 = (f32x4)0.0f, cs1 = (f32x4)0.0f;

#define STEP(t, CA, CB, NA, NB2)                                               \
    {                                                                          \
        if ((t) < 9) {                                                         \
            _Pragma("unroll")                                                  \
            for (int s = 0; s < 8; ++s) {                                      \
                NA[s] = *(const f32x4*)(xp + ((t) + 1) * DIN + s * 32);        \
                NB2[s] = *(const f32x4*)(xp + ((t) + 1) * DIN + s * 32 + 4);   \
            }                                                                  \
        }                                                                      \
        f32x4 ac0[4] = {b0[0], b0[1], b0[2], b0[3]};                           \
        _Pragma("unroll")                                                      \
        for (int s = 0; s < 8; ++s) {                                          \
            float fv[8] = {CA[s].x, CA[s].y, CA[s].z, CA[s].w,                 \
                           CB[s].x, CB[s].y, CB[s].z, CB[s].w};                \
            half8 xh, xl;                                                      \
            _Pragma("unroll")                                                  \
            for (int j = 0; j < 8; ++j) {                                      \
                _Float16 hi = (_Float16)fv[j];                                 \
                xh[j] = hi;                                                    \
                xl[j] = (_Float16)(fv[j] - (float)hi);                         \
            }                                                                  \
            _Pragma("unroll")                                                  \
            for (int c = 0; c < 4; ++c) {                                      \
                half8 wf = Bl[(c * 8 + s) * 64 + l];                           \
                ac0[c] = __builtin_amdgcn_mfma_f32_16x16x32_f16(wf, xh, ac0[c], 0, 0, 0); \
                ac0[c] = __builtin_amdgcn_mfma_f32_16x16x32_f16(wf, xl, ac0[c], 0, 0, 0); \
            }                                                                  \
        }                                                                      \
        _Pragma("unroll")                                                      \
        for (int c = 0; c < 4; ++c)                                            \
            ac0[c] = __builtin_amdgcn_mfma_f32_16x16x16f16(w0f[c], h0f, ac0[c], 0, 0, 0); \
        f32x4 h0v;                                                             \
        _Pragma("unroll")                                                      \
        for (int r = 0; r < 4; ++r) {                                          \
            float iv = sigf(ac0[0][r]), fg = sigf(ac0[1][r]);                  \
            float gv = tanhf_(ac0[2][r]), ov = sigf(ac0[3][r]);                \
            cs0[r] = fg * cs0[r] + iv * gv;                                    \
            h0v[r] = ov * tanhf_(cs0[r]);                                      \
        }                                                                      \
        h0f[0] = (_Float16)h0v[0]; h0f[1] = (_Float16)h0v[1];                  \
        h0f[2] = (_Float16)h0v[2]; h0f[3] = (_Float16)h0v[3];                  \
        f32x4 ac1[4] = {b1[0], b1[1], b1[2], b1[3]};                           \
        _Pragma("unroll")                                                      \
        for (int c = 0; c < 4; ++c) {                                          \
            ac1[c] = __builtin_amdgcn_mfma_f32_16x16x16f16(w1f[c], h0f, ac1[c], 0, 0, 0); \
            ac1[c] = __builtin_amdgcn_mfma_f32_16x16x16f16(w2f[c], h1f, ac1[c], 0, 0, 0); \
        }                                                                      \
        f32x4 h1v;                                                             \
        _Pragma("unroll")                                                      \
        for (int r = 0; r < 4; ++r) {                                          \
            float iv = sigf(ac1[0][r]), fg = sigf(ac1[1][r]);                  \
            float gv = tanhf_(ac1[2][r]), ov = sigf(ac1[3][r]);                \
            cs1[r] = fg * cs1[r] + iv * gv;                                    \
            h1v[r] = ov * tanhf_(cs1[r]);                                      \
        }                                                                      \
        h1f[0] = (_Float16)h1v[0]; h1f[1] = (_Float16)h1v[1];                  \
        h1f[2] = (_Float16)h1v[2]; h1f[3] = (_Float16)h1v[3];                  \
        _Pragma("unroll")                                                      \
        for (int r = 0; r < 4; ++r)                                            \
            flatT[(size_t)((t) * 16 + ((l >> 4) << 2) + r) * NB + sb * 16 + (l & 15)] = (_Float16)h1v[r]; \
    }

    STEP(0, A0, B0, A1, B1)
    STEP(1, A1, B1, A0, B0)
    STEP(2, A0, B0, A1, B1)
    STEP(3, A1, B1, A0, B0)
    STEP(4, A0, B0, A1, B1)
    STEP(5, A1, B1, A0, B0)
    STEP(6, A0, B0, A1, B1)
    STEP(7, A1, B1, A0, B0)
    STEP(8, A0, B0, A1, B1)
    STEP(9, A1, B1, A0, B0)
#undef STEP
}

// K2: BN stats directly from column-major flatT (coalesced).
__global__ __launch_bounds__(256) void k_bn(
        const _Float16* __restrict__ flatT, const float* __restrict__ gamma,
        const float* __restrict__ beta, float* __restrict__ scale,
        float* __restrict__ shift) {
    const int f = blockIdx.x;
    const int tid = threadIdx.x;
    const _Float16* col = flatT + (size_t)f * NB;
    float s = 0.0f, q = 0.0f;
    #pragma unroll 8
    for (int i = tid; i < NB; i += 256) {
        float v = (float)col[i];
        s += v; q += v * v;
    }
    #pragma unroll
    for (int o = 32; o > 0; o >>= 1) {
        s += __shfl_down(s, o, 64);
        q += __shfl_down(q, o, 64);
    }
    __shared__ float rs[4], rq[4];
    const int wv = tid >> 6;
    if ((tid & 63) == 0) { rs[wv] = s; rq[wv] = q; }
    __syncthreads();
    if (tid == 0) {
        float S = rs[0] + rs[1] + rs[2] + rs[3];
        float Q = rq[0] + rq[1] + rq[2] + rq[3];
        float mean = S * (1.0f / NB);
        float var = Q * (1.0f / NB) - mean * mean;
        float sc = gamma[f] * rsqrtf(var + 1e-5f);
        scale[f] = sc;
        shift[f] = beta[f] - mean * sc;
    }
}

// K3: BN-apply + LeakyReLU + concat + FC(162->2) + softmax.
// One thread per sample; flatT reads coalesced; scalar weights.
__global__ __launch_bounds__(256) void k_fc(
        const _Float16* __restrict__ flatT, const float* __restrict__ scale,
        const float* __restrict__ shift, const float* __restrict__ ag,
        const float* __restrict__ fcw, const float* __restrict__ fcb,
        float* __restrict__ out) {
    const int smp = blockIdx.x * 256 + threadIdx.x;
    float p0 = 0.0f, p1 = 0.0f;
    #pragma unroll 8
    for (int f = 0; f < NF; ++f) {
        float xn = (float)flatT[(size_t)f * NB + smp] * scale[f] + shift[f];
        float a = xn >= 0.0f ? xn : 0.01f * xn;
        p0 += a * fcw[f];
        p1 += a * fcw[162 + f];
    }
    float a0 = ag[(size_t)smp * 2 + 0], a1 = ag[(size_t)smp * 2 + 1];
    float l0 = p0 + a0 * fcw[160] + a1 * fcw[161] + fcb[0];
    float l1 = p1 + a0 * fcw[162 + 160] + a1 * fcw[162 + 161] + fcb[1];
    float m = fmaxf(l0, l1);
    float e0 = __expf(l0 - m), e1 = __expf(l1 - m);
    float inv = 1.0f / (e0 + e1);
    out[(size_t)smp * 2 + 0] = e0 * inv;
    out[(size_t)smp * 2 + 1] = e1 * inv;
}

extern "C" void kernel_launch(void* const* d_in, const int* in_sizes, int n_in,
                              void* d_out, int out_size, void* d_ws, size_t ws_size,
                              hipStream_t stream) {
    const float* x     = (const float*)d_in[0];
    const float* ag    = (const float*)d_in[1];
    const float* wih0  = (const float*)d_in[2];
    const float* whh0  = (const float*)d_in[3];
    const float* bih0  = (const float*)d_in[4];
    const float* bhh0  = (const float*)d_in[5];
    const float* wih1  = (const float*)d_in[6];
    const float* whh1  = (const float*)d_in[7];
    const float* bih1  = (const float*)d_in[8];
    const float* bhh1  = (const float*)d_in[9];
    const float* gamma = (const float*)d_in[10];
    const float* beta  = (const float*)d_in[11];
    const float* fcw   = (const float*)d_in[12];
    const float* fcb   = (const float*)d_in[13];
    float* out = (float*)d_out;

    float* ws = (float*)d_ws;
    _Float16* flatT = (_Float16*)ws;   // [NF][NB] = 2,621,440 halfs = 1,310,720 f32 slots
    float* scale = ws + 1310720;       // 160  (AFTER flatT — R18 bug was 655360, aliasing flatT)
    float* shift = ws + 1310880;       // 160

    k_mega<<<dim3(256), dim3(256), 0, stream>>>(x, wih0, bih0, bhh0, whh0,
                                                wih1, whh1, bih1, bhh1, flatT);
    k_bn<<<dim3(NF),    dim3(256), 0, stream>>>(flatT, gamma, beta, scale, shift);
    k_fc<<<dim3(64),    dim3(256), 0, stream>>>(flatT, scale, shift, ag, fcw, fcb, out);
}